// Round 12
// baseline (2623.967 us; speedup 1.0000x reference)
//
#include <hip/hip_runtime.h>
#include <hip/hip_bf16.h>
#include <cstdint>

#define DEVI __device__ __forceinline__

typedef __attribute__((ext_vector_type(8))) short bf16x8_t;   // 8 bf16 in 4 VGPRs
typedef __attribute__((ext_vector_type(4))) float f32x4_t;    // MFMA C/D

DEVI float bf2f(unsigned short u) {
    union { uint32_t i; float f; } v; v.i = ((uint32_t)u) << 16; return v.f;
}
DEVI unsigned short f2bf(float f) {
    union { float f; uint32_t i; } v; v.f = f;
    uint32_t i = v.i;
    uint32_t r = (i + 0x7FFFu + ((i >> 16) & 1u)) >> 16;   // RNE
    return (unsigned short)r;
}

DEVI f32x4_t mfma16(bf16x8_t a, bf16x8_t b, f32x4_t c) {
    return __builtin_amdgcn_mfma_f32_16x16x32_bf16(a, b, c, 0, 0, 0);
}

#define GL2LDS(g, l) __builtin_amdgcn_global_load_lds( \
    (const __attribute__((address_space(1))) void*)(g), \
    (__attribute__((address_space(3))) void*)(l), 16, 0, 0)

// ------------------------------------------------- fused embed + layer-0 LN (192 thr)
__global__ void k_embed_ln(const int* __restrict__ ids, const float* __restrict__ wte,
                           const float* __restrict__ wpe, const float* __restrict__ w,
                           const float* __restrict__ b, float* __restrict__ h,
                           unsigned short* __restrict__ x) {
    int m = blockIdx.x;
    int s = m & 1023;
    int id = ids[m];
    int t = threadIdx.x;           // 0..191
    const float4 te = *reinterpret_cast<const float4*>(wte + (size_t)id * 768 + t * 4);
    const float4 pe = *reinterpret_cast<const float4*>(wpe + (size_t)s * 768 + t * 4);
    float4 v; v.x = te.x + pe.x; v.y = te.y + pe.y; v.z = te.z + pe.z; v.w = te.w + pe.w;
    *reinterpret_cast<float4*>(h + (size_t)m * 768 + t * 4) = v;
    float sm = v.x + v.y + v.z + v.w;
    float ss = v.x * v.x + v.y * v.y + v.z * v.z + v.w * v.w;
#pragma unroll
    for (int o = 32; o > 0; o >>= 1) { sm += __shfl_down(sm, o); ss += __shfl_down(ss, o); }
    __shared__ float red[8];
    int wid = t >> 6, lane = t & 63;
    if (lane == 0) { red[wid] = sm; red[4 + wid] = ss; }
    __syncthreads();
    if (t == 0) {
        float S = red[0] + red[1] + red[2];
        float SS = red[4] + red[5] + red[6];
        float mean = S * (1.f / 768.f);
        float var = SS * (1.f / 768.f) - mean * mean;
        red[0] = mean; red[1] = rsqrtf(var + 1e-5f);
    }
    __syncthreads();
    float mean = red[0], rst = red[1];
    float4 wv = *reinterpret_cast<const float4*>(w + t * 4);
    float4 bv = *reinterpret_cast<const float4*>(b + t * 4);
    ushort4 o4;
    o4.x = f2bf((v.x - mean) * rst * wv.x + bv.x);
    o4.y = f2bf((v.y - mean) * rst * wv.y + bv.y);
    o4.z = f2bf((v.z - mean) * rst * wv.z + bv.z);
    o4.w = f2bf((v.w - mean) * rst * wv.w + bv.w);
    *reinterpret_cast<ushort4*>(x + (size_t)m * 768 + t * 4) = o4;
}

// --------------------------------------- fused: h += p0+p1+bias ; x = LN(h)  (192 thr)
__global__ void k_ln_red(const unsigned short* __restrict__ part, const float* __restrict__ ab,
                         const float* __restrict__ w, const float* __restrict__ b,
                         float* __restrict__ h, unsigned short* __restrict__ x) {
    int m = blockIdx.x;
    int t = threadIdx.x;           // 0..191
    size_t o0 = (size_t)m * 768 + t * 4;
    float4 hv = *reinterpret_cast<const float4*>(h + o0);
    ushort4 q0 = *reinterpret_cast<const ushort4*>(part + o0);
    ushort4 q1 = *reinterpret_cast<const ushort4*>(part + 4096ull * 768 + o0);
    float4 av = *reinterpret_cast<const float4*>(ab + t * 4);
    float4 v;
    v.x = hv.x + bf2f(q0.x) + bf2f(q1.x) + av.x;
    v.y = hv.y + bf2f(q0.y) + bf2f(q1.y) + av.y;
    v.z = hv.z + bf2f(q0.z) + bf2f(q1.z) + av.z;
    v.w = hv.w + bf2f(q0.w) + bf2f(q1.w) + av.w;
    float sm = v.x + v.y + v.z + v.w;
    float ss = v.x * v.x + v.y * v.y + v.z * v.z + v.w * v.w;
#pragma unroll
    for (int o = 32; o > 0; o >>= 1) { sm += __shfl_down(sm, o); ss += __shfl_down(ss, o); }
    __shared__ float red[8];
    int wid = t >> 6, lane = t & 63;
    if (lane == 0) { red[wid] = sm; red[4 + wid] = ss; }
    __syncthreads();
    if (t == 0) {
        float S = red[0] + red[1] + red[2];
        float SS = red[4] + red[5] + red[6];
        float mean = S * (1.f / 768.f);
        float var = SS * (1.f / 768.f) - mean * mean;
        red[0] = mean; red[1] = rsqrtf(var + 1e-5f);
    }
    __syncthreads();
    float mean = red[0], rst = red[1];
    *reinterpret_cast<float4*>(h + o0) = v;
    float4 wv = *reinterpret_cast<const float4*>(w + t * 4);
    float4 bv = *reinterpret_cast<const float4*>(b + t * 4);
    ushort4 o4;
    o4.x = f2bf((v.x - mean) * rst * wv.x + bv.x);
    o4.y = f2bf((v.y - mean) * rst * wv.y + bv.y);
    o4.z = f2bf((v.z - mean) * rst * wv.z + bv.z);
    o4.w = f2bf((v.w - mean) * rst * wv.w + bv.w);
    *reinterpret_cast<ushort4*>(x + (size_t)m * 768 + t * 4) = o4;
}

// ------------------------------------------------- transpose fp32[K][N] -> bf16[Npad][K]
__global__ void k_transpose(const float* __restrict__ W, unsigned short* __restrict__ Bt,
                            int K, int N, int Npad) {
    __shared__ float tile[64][65];
    int tx = threadIdx.x, ty = threadIdx.y;     // (16, 16)
    int n0 = blockIdx.x * 64, k0 = blockIdx.y * 64;
    size_t l = blockIdx.z;
    W += l * (size_t)K * N;
    Bt += l * (size_t)Npad * K;
    if (n0 + 64 <= N) {
#pragma unroll
        for (int i = 0; i < 4; i++) {
            int kr = ty * 4 + i;
            float4 v = *reinterpret_cast<const float4*>(W + (size_t)(k0 + kr) * N + n0 + tx * 4);
            tile[kr][tx * 4 + 0] = v.x;
            tile[kr][tx * 4 + 1] = v.y;
            tile[kr][tx * 4 + 2] = v.z;
            tile[kr][tx * 4 + 3] = v.w;
        }
    } else {
#pragma unroll
        for (int i = 0; i < 4; i++) {
            int kr = ty * 4 + i;
#pragma unroll
            for (int j = 0; j < 4; j++) {
                int n = n0 + tx * 4 + j;
                tile[kr][tx * 4 + j] = (n < N) ? W[(size_t)(k0 + kr) * N + n] : 0.f;
            }
        }
    }
    __syncthreads();
#pragma unroll
    for (int i = 0; i < 4; i++) {
        int n = n0 + ty * 4 + i;
        ushort4 o;
        o.x = f2bf(tile[tx * 4 + 0][ty * 4 + i]);
        o.y = f2bf(tile[tx * 4 + 1][ty * 4 + i]);
        o.z = f2bf(tile[tx * 4 + 2][ty * 4 + i]);
        o.w = f2bf(tile[tx * 4 + 3][ty * 4 + i]);
        *reinterpret_cast<ushort4*>(Bt + (size_t)n * K + k0 + tx * 4) = o;
    }
}

// ---------------------------------------------------------------- GEMM (mid-size)
template <int BM, int BIAS, int GELU, int OUTBF16, int SPLITK>
__launch_bounds__(256, 2)
__global__ void k_gemm(const unsigned short* __restrict__ A,
                       const unsigned short* __restrict__ Bt,
                       const float* __restrict__ bias,
                       void* __restrict__ out,
                       int M, int N, int K) {
    constexpr int MF = BM / 32;
    constexpr int HALF = (BM + 128) * 64;
    __shared__ char smem_raw[2 * HALF];

    int t = threadIdx.x;
    int bm = blockIdx.x, bn = blockIdx.y;
    int kc = (SPLITK > 1) ? blockIdx.z : 0;
    int KC = K / SPLITK;

    int rowA0 = bm * BM, rowB0 = bn * 128;
    int lane = t & 63, w = t >> 6;
    int wr = w >> 1, wc = w & 1;

    const unsigned short* ga0 = A  + (size_t)(rowA0 + (t >> 2)) * K + kc * KC + (t & 3) * 8;
    const unsigned short* ga1 = ga0 + (size_t)64 * K;
    const unsigned short* gb0 = Bt + (size_t)(rowB0 + (t >> 2)) * K + kc * KC + (t & 3) * 8;
    const unsigned short* gb1 = gb0 + (size_t)64 * K;

    auto stage = [&](int buf, int ktile) {
        char* dst = smem_raw + buf * HALF + t * 16;
        int kt = ktile * 32;
        GL2LDS(ga0 + kt, dst);
        if constexpr (BM == 128) GL2LDS(ga1 + kt, dst + 4096);
        char* dstB = dst + BM * 64;
        GL2LDS(gb0 + kt, dstB);
        GL2LDS(gb1 + kt, dstB + 4096);
    };

    f32x4_t acc[MF][4] = {};

    int rA = wr * (BM / 2) + (lane & 15);
    int rB = wc * 64 + (lane & 15);
    int kofs = (lane >> 4) * 8;

    const int NT = KC / 32;
    stage(0, 0);
    __syncthreads();
    int cur = 0;
    for (int kt = 0; kt < NT; kt++) {
        if (kt + 1 < NT) stage(cur ^ 1, kt + 1);
        const unsigned short* As = (const unsigned short*)(smem_raw + cur * HALF);
        const unsigned short* Bs = As + BM * 32;
        bf16x8_t a[MF], b[4];
#pragma unroll
        for (int m = 0; m < MF; m++)
            a[m] = *reinterpret_cast<const bf16x8_t*>(As + (rA + m * 16) * 32 + kofs);
#pragma unroll
        for (int n = 0; n < 4; n++)
            b[n] = *reinterpret_cast<const bf16x8_t*>(Bs + (rB + n * 16) * 32 + kofs);
#pragma unroll
        for (int m = 0; m < MF; m++)
#pragma unroll
            for (int n = 0; n < 4; n++)
                acc[m][n] = mfma16(a[m], b[n], acc[m][n]);
        __syncthreads();
        cur ^= 1;
    }

    if constexpr (OUTBF16) {
        int colBase = bn * 128 + wc * 64 + (lane & 15);
        int rowBase = bm * BM + wr * (BM / 2) + ((lane >> 4) << 2);
#pragma unroll
        for (int n = 0; n < 4; n++) {
            int col = colBase + n * 16;
            float bv = 0.f;
            if (BIAS) bv = bias[col];
#pragma unroll
            for (int m = 0; m < MF; m++) {
                int row0 = rowBase + m * 16;
#pragma unroll
                for (int r = 0; r < 4; r++) {
                    int row = row0 + r;
                    float v = acc[m][n][r] + bv;
                    if (GELU) v = 0.5f * v * (1.f + erff(v * 0.70710678118f));
                    ((unsigned short*)out)[(size_t)row * N + col] = f2bf(v);
                }
            }
        }
    } else {
        auto epi = (unsigned short (*)[16][72])smem_raw;
        unsigned short* op_base = (unsigned short*)out + (size_t)kc * M * N;
        int rowBase0 = bm * BM + wr * (BM / 2);
        int colBase0 = bn * 128 + wc * 64;
#pragma unroll
        for (int m = 0; m < MF; m++) {
#pragma unroll
            for (int n = 0; n < 4; n++)
#pragma unroll
                for (int r = 0; r < 4; r++)
                    epi[w][(lane >> 4) * 4 + r][n * 16 + (lane & 15)] = f2bf(acc[m][n][r]);
            __syncthreads();
#pragma unroll
            for (int rr = 0; rr < 4; rr++) {
                int lr = (lane >> 4) * 4 + rr;
                int grow = rowBase0 + m * 16 + lr;
                int gcol = colBase0 + (lane & 15) * 4;
                ushort4 v4 = *reinterpret_cast<ushort4*>(&epi[w][lr][(lane & 15) * 4]);
                *reinterpret_cast<ushort4*>(op_base + (size_t)grow * N + gcol) = v4;
            }
            __syncthreads();
        }
    }
}

// ---------------------------------------------------------------- lm-head GEMM (256^2 deep pipeline)
__launch_bounds__(512, 1)
__global__ void k_lm(const unsigned short* __restrict__ A,
                     const unsigned short* __restrict__ Bt,
                     float* __restrict__ out) {
    constexpr int K = 768;
    constexpr int NT = K / 64;                 // 12 K-tiles
    __shared__ char smem[131072];              // 2 x (A 32KB | B 32KB)

    int t = threadIdx.x;
    int bm = blockIdx.x, bn = blockIdx.y;      // natural order, bm fastest
    int lane = t & 63, w = t >> 6;
    int wm = w >> 2, wn = w & 3;               // 2 x 4 waves
    int q = lane >> 4, l15 = lane & 15, l7 = lane & 7;

    int srow = t >> 3;                         // 0..63 per issue
    int sslot = (t & 7) ^ (srow & 7);
    const unsigned short* gA = A  + (size_t)(bm * 256 + srow) * K + sslot * 8;
    const unsigned short* gB = Bt + (size_t)(bn * 256 + srow) * K + sslot * 8;

    auto stage = [&](int buf, int ktile) {
        char* dst = smem + buf * 65536 + t * 16;
        int ko = ktile * 64;
#pragma unroll
        for (int i = 0; i < 4; i++)
            GL2LDS(gA + (size_t)(i * 64) * K + ko, dst + i * 8192);
#pragma unroll
        for (int i = 0; i < 4; i++)
            GL2LDS(gB + (size_t)(i * 64) * K + ko, dst + 32768 + i * 8192);
    };

    f32x4_t acc[8][4] = {};

    stage(0, 0);
    int cur = 0;
    for (int kt = 0; kt < NT; kt++) {
        if (kt + 1 < NT) {
            stage(cur ^ 1, kt + 1);
            asm volatile("s_waitcnt vmcnt(8)" ::: "memory");
        } else {
            asm volatile("s_waitcnt vmcnt(0)" ::: "memory");
        }
        __builtin_amdgcn_s_barrier();
        asm volatile("" ::: "memory");
        const char* Ab = smem + cur * 65536;
        const char* Bb = Ab + 32768;

        bf16x8_t bfr[4][2];
#pragma unroll
        for (int nf = 0; nf < 4; nf++)
#pragma unroll
            for (int ks = 0; ks < 2; ks++) {
                int row = wn * 64 + nf * 16 + l15;
                int slot = (ks * 4 + q) ^ l7;
                bfr[nf][ks] = *reinterpret_cast<const bf16x8_t*>(Bb + row * 128 + slot * 16);
            }
#pragma unroll
        for (int p = 0; p < 4; p++) {
            bf16x8_t afr[2][2];
#pragma unroll
            for (int mi = 0; mi < 2; mi++)
#pragma unroll
                for (int ks = 0; ks < 2; ks++) {
                    int row = wm * 128 + (p * 2 + mi) * 16 + l15;
                    int slot = (ks * 4 + q) ^ l7;
                    afr[mi][ks] = *reinterpret_cast<const bf16x8_t*>(Ab + row * 128 + slot * 16);
                }
            asm volatile("s_waitcnt lgkmcnt(0)" ::: "memory");
            __builtin_amdgcn_sched_barrier(0);
            __builtin_amdgcn_s_setprio(1);
#pragma unroll
            for (int mi = 0; mi < 2; mi++)
#pragma unroll
                for (int nf = 0; nf < 4; nf++)
#pragma unroll
                    for (int ks = 0; ks < 2; ks++)
                        acc[p * 2 + mi][nf] = mfma16(afr[mi][ks], bfr[nf][ks], acc[p * 2 + mi][nf]);
            __builtin_amdgcn_s_setprio(0);
        }
        asm volatile("" ::: "memory");
        __builtin_amdgcn_s_barrier();
        cur ^= 1;
    }

    float* epi = (float*)smem + w * (16 * 68);
#pragma unroll
    for (int mf = 0; mf < 8; mf++) {
#pragma unroll
        for (int nf = 0; nf < 4; nf++)
#pragma unroll
            for (int r = 0; r < 4; r++)
                epi[(q * 4 + r) * 68 + nf * 16 + l15] = acc[mf][nf][r];
        asm volatile("s_waitcnt lgkmcnt(0)" ::: "memory");
#pragma unroll
        for (int rr = 0; rr < 4; rr++) {
            int lr = q * 4 + rr;
            int grow = bm * 256 + wm * 128 + mf * 16 + lr;
            int col0 = bn * 256 + wn * 64 + l15;
            float* op = out + (size_t)grow * 50257 + col0;
#pragma unroll
            for (int e = 0; e < 4; e++) {
                if (col0 + e * 16 < 50257) op[e * 16] = epi[lr * 68 + l15 + e * 16];
            }
        }
        asm volatile("s_waitcnt lgkmcnt(0)" ::: "memory");
    }
}

// ---------------------------------------------------------------- flash attention
// grid (16 q-tiles, 48 bh), 256 thr. KV tile = 64. K staged in LDS (rule #21),
// swapped QK^T (lane-local key reduce), defer-max THR=8.
// V: 2 keys x 8 d per lane -> transpose write packed as 8 x ds_write_b32
// (adjacent keys contiguous in Vt[d][key]); Ps packed as 4 x ds_write_b64.
__launch_bounds__(256, 2)
__global__ void k_attn(const unsigned short* __restrict__ qkv, unsigned short* __restrict__ y) {
    __shared__ unsigned short Kb[3][4096];       // [key=64][d=64], src-swizzled
    __shared__ unsigned short Vt[2][4096];       // [d=64][key=64], XOR-swizzled
    __shared__ unsigned short Ps[4][16 * 72];    // per-wave P rows [q][k], stride 72

    int bh = blockIdx.y;
    int b = bh / 12, h = bh % 12;
    int qt = blockIdx.x;
    int t = threadIdx.x, lane = t & 63, w = t >> 6;
    const size_t ldq = 2304;
    const unsigned short* base = qkv + (size_t)b * 1024 * ldq + h * 64;
    const unsigned short* Kg = base + 768;
    const unsigned short* Vg = base + 1536;

    int srow = t >> 3;
    int lslot = (t & 7) ^ (srow & 7);
    auto stageK = [&](int buf, int kt) {
#pragma unroll
        for (int i = 0; i < 2; i++) {
            const unsigned short* src = Kg + (size_t)(kt * 64 + i * 32 + srow) * ldq + lslot * 8;
            GL2LDS(src, (char*)&Kb[buf][0] + i * 4096 + t * 16);
        }
    };

    bf16x8_t qf[2];
    int qrow = qt * 64 + w * 16 + (lane & 15);
#pragma unroll
    for (int kb = 0; kb < 2; kb++)
        qf[kb] = *reinterpret_cast<const bf16x8_t*>(base + (size_t)qrow * ldq + kb * 32 + (lane >> 4) * 8);

    f32x4_t o[4] = {};
    float m = -1e30f, l = 0.f;      // running max / denom for q = lane&15
    const float scale = 0.125f;

    // V reg staging: lane covers keys {2*g2, 2*g2+1} x d in [dbase, dbase+8)
    int g2 = lane & 31;
    int dbase = ((lane >> 5) + w * 2) * 8;
    union VU { uint4 v[2]; unsigned short e[16]; };   // e[i*8+j]: key 2*g2+i, d dbase+j
    VU vv, vvn;
    auto loadV = [&](VU& u, int kt) {
        const unsigned short* p0 = Vg + (size_t)(kt * 64 + 2 * g2) * ldq + dbase;
        u.v[0] = *reinterpret_cast<const uint4*>(p0);
        u.v[1] = *reinterpret_cast<const uint4*>(p0 + ldq);
    };
    loadV(vv, 0);
    stageK(0, 0);
    __syncthreads();

    int cur = 0;
    for (int kt = 0; kt < 16; kt++) {
        // ---- write V tile kt (transposed; packed b32: 2 adjacent keys)
        char* vbuf = (char*)&Vt[cur][0];
#pragma unroll
        for (int j = 0; j < 8; j++) {
            int d = dbase + j;
            uint32_t pk = (uint32_t)vv.e[j] | ((uint32_t)vv.e[8 + j] << 16);
            uint32_t byte = (uint32_t)(d * 128 + g2 * 4) ^ (uint32_t)((d & 7) << 4);
            *(uint32_t*)(vbuf + byte) = pk;
        }
        __syncthreads();
        if (kt < 15) {
            stageK((kt + 1) % 3, kt + 1);
            loadV(vvn, kt + 1);
        }
        // ---- S^T = K Q^T  (s[n][r]: key = n*16+(lane>>4)*4+r, q = lane&15)
        const char* kbuf = (const char*)&Kb[kt % 3][0];
        f32x4_t s[4] = {};
#pragma unroll
        for (int kb = 0; kb < 2; kb++) {
#pragma unroll
            for (int n = 0; n < 4; n++) {
                int row = n * 16 + (lane & 15);
                int pslot = (kb * 4 + (lane >> 4)) ^ (lane & 7);
                bf16x8_t kf = *reinterpret_cast<const bf16x8_t*>(kbuf + row * 128 + pslot * 16);
                s[n] = mfma16(kf, qf[kb], s[n]);
            }
        }
        // ---- softmax: key-reduce in-register; 2 shfl merge
        float tmax = s[0][0];
#pragma unroll
        for (int n = 0; n < 4; n++)
#pragma unroll
            for (int r = 0; r < 4; r++) tmax = fmaxf(tmax, s[n][r]);
        tmax = fmaxf(tmax, __shfl_xor(tmax, 16));
        tmax = fmaxf(tmax, __shfl_xor(tmax, 32));
        tmax *= scale;
        if (__any(tmax > m + 8.f)) {            // rescale path (runs ~once)
            float mnew = fmaxf(m, tmax);
            float corr = __expf(m - mnew);
            m = mnew;
            l *= corr;
#pragma unroll
            for (int r = 0; r < 4; r++) {
                float cr = __shfl(corr, (lane & 48) | ((lane >> 4) * 4 + r));
#pragma unroll
                for (int n = 0; n < 4; n++) o[n][r] *= cr;
            }
        }
        float psum = 0.f;
#pragma unroll
        for (int n = 0; n < 4; n++) {
            ushort4 pk;
            unsigned short* pp = (unsigned short*)&pk;
#pragma unroll
            for (int r = 0; r < 4; r++) {
                float p = __expf(s[n][r] * scale - m);
                psum += p;
                pp[r] = f2bf(p);
            }
            *reinterpret_cast<ushort4*>(&Ps[w][(lane & 15) * 72 + n * 16 + (lane >> 4) * 4]) = pk;
        }
        psum += __shfl_xor(psum, 16);
        psum += __shfl_xor(psum, 32);
        l += psum;
        // ---- O += P V
#pragma unroll
        for (int kb = 0; kb < 2; kb++) {
            bf16x8_t pf = *reinterpret_cast<const bf16x8_t*>(
                &Ps[w][(lane & 15) * 72 + kb * 32 + (lane >> 4) * 8]);
#pragma unroll
            for (int n = 0; n < 4; n++) {
                int d = n * 16 + (lane & 15);
                uint32_t byte = (uint32_t)(d * 128 + (kb * 32 + (lane >> 4) * 8) * 2)
                                ^ (uint32_t)((d & 7) << 4);
                bf16x8_t vf = *reinterpret_cast<const bf16x8_t*>(vbuf + byte);
                o[n] = mfma16(pf, vf, o[n]);
            }
        }
        vv = vvn;
        cur ^= 1;
    }
    float linv[4];
#pragma unroll
    for (int r = 0; r < 4; r++)
        linv[r] = 1.f / __shfl(l, (lane & 48) | ((lane >> 4) * 4 + r));
#pragma unroll
    for (int n = 0; n < 4; n++) {
#pragma unroll
        for (int r = 0; r < 4; r++) {
            float val = o[n][r] * linv[r];
            int row = qt * 64 + w * 16 + (lane >> 4) * 4 + r;
            y[((size_t)(b * 1024 + row)) * 768 + h * 64 + n * 16 + (lane & 15)] = f2bf(val);
        }
    }
}

// ---------------------------------------------------------------- host
extern "C" void kernel_launch(void* const* d_in, const int* in_sizes, int n_in,
                              void* d_out, int out_size, void* d_ws, size_t ws_size,
                              hipStream_t stream) {
    const int*   ids   = (const int*)d_in[0];
    const float* wte   = (const float*)d_in[1];
    const float* wpe   = (const float*)d_in[2];
    const float* ln1w  = (const float*)d_in[3];
    const float* ln1b  = (const float*)d_in[4];
    const float* attnw = (const float*)d_in[5];
    const float* attnb = (const float*)d_in[6];
    const float* atpw  = (const float*)d_in[7];
    const float* atpb  = (const float*)d_in[8];
    const float* ln2w  = (const float*)d_in[9];
    const float* ln2b  = (const float*)d_in[10];
    const float* fcw   = (const float*)d_in[11];
    const float* fcb   = (const float*)d_in[12];
    const float* pjw   = (const float*)d_in[13];
    const float* pjb   = (const float*)d_in[14];
    const float* lnfw  = (const float*)d_in[15];
    const float* lnfb  = (const float*)d_in[16];
    const float* lmw   = (const float*)d_in[17];
    float* out = (float*)d_out;

    char* ws = (char*)d_ws;
    size_t off = 0;
    auto alloc = [&](size_t bytes) -> void* {
        void* p = ws + off;
        off += (bytes + 255) & ~(size_t)255;
        return p;
    };
    float*          h      = (float*)alloc(4096ull * 768 * 4);
    unsigned short* x      = (unsigned short*)alloc(4096ull * 768 * 2);
    unsigned short* qkvb   = (unsigned short*)alloc(4096ull * 2304 * 2);
    unsigned short* y      = (unsigned short*)alloc(4096ull * 768 * 2);
    unsigned short* u      = (unsigned short*)alloc(4096ull * 3072 * 2);
    unsigned short* part   = (unsigned short*)alloc(2ull * 4096 * 768 * 2);
    unsigned short* attnwT = (unsigned short*)alloc(12ull * 2304 * 768 * 2);
    unsigned short* atpwT  = (unsigned short*)alloc(12ull * 768 * 768 * 2);
    unsigned short* fcwT   = (unsigned short*)alloc(12ull * 3072 * 768 * 2);
    unsigned short* pjwT   = (unsigned short*)alloc(12ull * 768 * 3072 * 2);
    unsigned short* lmwT   = (unsigned short*)alloc(50432ull * 768 * 2);

    dim3 tb(16, 16);
    k_transpose<<<dim3(2304 / 64, 768 / 64, 12), tb, 0, stream>>>(attnw, attnwT, 768, 2304, 2304);
    k_transpose<<<dim3(768 / 64, 768 / 64, 12), tb, 0, stream>>>(atpw, atpwT, 768, 768, 768);
    k_transpose<<<dim3(3072 / 64, 768 / 64, 12), tb, 0, stream>>>(fcw, fcwT, 768, 3072, 3072);
    k_transpose<<<dim3(768 / 64, 3072 / 64, 12), tb, 0, stream>>>(pjw, pjwT, 3072, 768, 768);
    k_transpose<<<dim3(50432 / 64, 768 / 64, 1), tb, 0, stream>>>(lmw, lmwT, 768, 50257, 50432);

    k_embed_ln<<<4096, 192, 0, stream>>>(ids, wte, wpe, ln1w, ln1b, h, x);

    for (int l = 0; l < 12; l++) {
        // qkv: 128^2 2-phase, bias bf16 epilogue (full-chip grid)
        k_gemm<128, 1, 0, 1, 1><<<dim3(32, 18), 256, 0, stream>>>(
            x, attnwT + (size_t)l * 2304 * 768, attnb + l * 2304, qkvb,
            4096, 2304, 768);
        k_attn<<<dim3(16, 48), 256, 0, stream>>>(qkvb, y);
        // atp: split-K=2 bf16 partials
        k_gemm<64, 0, 0, 0, 2><<<dim3(64, 6, 2), 256, 0, stream>>>(
            y, atpwT + (size_t)l * 768 * 768, nullptr, part,
            4096, 768, 768);
        k_ln_red<<<4096, 192, 0, stream>>>(part, atpb + l * 768,
            ln2w + l * 768, ln2b + l * 768, h, x);
        // fc: 128^2 2-phase, bias+gelu bf16 epilogue
        k_gemm<128, 1, 1, 1, 1><<<dim3(32, 24), 256, 0, stream>>>(
            x, fcwT + (size_t)l * 3072 * 768, fcb + l * 3072, u,
            4096, 3072, 768);
        // pj: split-K=2 bf16 partials
        k_gemm<64, 0, 0, 0, 2><<<dim3(64, 6, 2), 256, 0, stream>>>(
            u, pjwT + (size_t)l * 768 * 3072, nullptr, part,
            4096, 768, 3072);
        const float* nw = (l < 11) ? ln1w + (l + 1) * 768 : lnfw;
        const float* nb = (l < 11) ? ln1b + (l + 1) * 768 : lnfb;
        k_ln_red<<<4096, 192, 0, stream>>>(part, pjb + l * 768, nw, nb, h, x);
    }
    k_lm<<<dim3(16, 197), 512, 0, stream>>>(x, lmwT, out);
}

// Round 13
// 2513.070 us; speedup vs baseline: 1.0441x; 1.0441x over previous
//
#include <hip/hip_runtime.h>
#include <hip/hip_bf16.h>
#include <cstdint>

#define DEVI __device__ __forceinline__

typedef __attribute__((ext_vector_type(8))) short bf16x8_t;   // 8 bf16 in 4 VGPRs
typedef __attribute__((ext_vector_type(4))) float f32x4_t;    // MFMA C/D

DEVI float bf2f(unsigned short u) {
    union { uint32_t i; float f; } v; v.i = ((uint32_t)u) << 16; return v.f;
}
DEVI unsigned short f2bf(float f) {
    union { float f; uint32_t i; } v; v.f = f;
    uint32_t i = v.i;
    uint32_t r = (i + 0x7FFFu + ((i >> 16) & 1u)) >> 16;   // RNE
    return (unsigned short)r;
}

DEVI f32x4_t mfma16(bf16x8_t a, bf16x8_t b, f32x4_t c) {
    return __builtin_amdgcn_mfma_f32_16x16x32_bf16(a, b, c, 0, 0, 0);
}

#define GL2LDS(g, l) __builtin_amdgcn_global_load_lds( \
    (const __attribute__((address_space(1))) void*)(g), \
    (__attribute__((address_space(3))) void*)(l), 16, 0, 0)

// ------------------------------------------------- fused embed + layer-0 LN (192 thr)
__global__ void k_embed_ln(const int* __restrict__ ids, const float* __restrict__ wte,
                           const float* __restrict__ wpe, const float* __restrict__ w,
                           const float* __restrict__ b, float* __restrict__ h,
                           unsigned short* __restrict__ x) {
    int m = blockIdx.x;
    int s = m & 1023;
    int id = ids[m];
    int t = threadIdx.x;           // 0..191
    const float4 te = *reinterpret_cast<const float4*>(wte + (size_t)id * 768 + t * 4);
    const float4 pe = *reinterpret_cast<const float4*>(wpe + (size_t)s * 768 + t * 4);
    float4 v; v.x = te.x + pe.x; v.y = te.y + pe.y; v.z = te.z + pe.z; v.w = te.w + pe.w;
    *reinterpret_cast<float4*>(h + (size_t)m * 768 + t * 4) = v;
    float sm = v.x + v.y + v.z + v.w;
    float ss = v.x * v.x + v.y * v.y + v.z * v.z + v.w * v.w;
#pragma unroll
    for (int o = 32; o > 0; o >>= 1) { sm += __shfl_down(sm, o); ss += __shfl_down(ss, o); }
    __shared__ float red[8];
    int wid = t >> 6, lane = t & 63;
    if (lane == 0) { red[wid] = sm; red[4 + wid] = ss; }
    __syncthreads();
    if (t == 0) {
        float S = red[0] + red[1] + red[2];
        float SS = red[4] + red[5] + red[6];
        float mean = S * (1.f / 768.f);
        float var = SS * (1.f / 768.f) - mean * mean;
        red[0] = mean; red[1] = rsqrtf(var + 1e-5f);
    }
    __syncthreads();
    float mean = red[0], rst = red[1];
    float4 wv = *reinterpret_cast<const float4*>(w + t * 4);
    float4 bv = *reinterpret_cast<const float4*>(b + t * 4);
    ushort4 o4;
    o4.x = f2bf((v.x - mean) * rst * wv.x + bv.x);
    o4.y = f2bf((v.y - mean) * rst * wv.y + bv.y);
    o4.z = f2bf((v.z - mean) * rst * wv.z + bv.z);
    o4.w = f2bf((v.w - mean) * rst * wv.w + bv.w);
    *reinterpret_cast<ushort4*>(x + (size_t)m * 768 + t * 4) = o4;
}

// --------------------------------------- fused: h += sum(parts)+bias ; x = LN(h)  (192 thr)
template <int NPART>
__global__ void k_ln_red(const unsigned short* __restrict__ part, const float* __restrict__ ab,
                         const float* __restrict__ w, const float* __restrict__ b,
                         float* __restrict__ h, unsigned short* __restrict__ x) {
    int m = blockIdx.x;
    int t = threadIdx.x;           // 0..191
    size_t o0 = (size_t)m * 768 + t * 4;
    float4 hv = *reinterpret_cast<const float4*>(h + o0);
    float4 av = *reinterpret_cast<const float4*>(ab + t * 4);
    float4 v;
    v.x = hv.x + av.x; v.y = hv.y + av.y; v.z = hv.z + av.z; v.w = hv.w + av.w;
#pragma unroll
    for (int p = 0; p < NPART; p++) {
        ushort4 q = *reinterpret_cast<const ushort4*>(part + (size_t)p * 4096 * 768 + o0);
        v.x += bf2f(q.x); v.y += bf2f(q.y); v.z += bf2f(q.z); v.w += bf2f(q.w);
    }
    float sm = v.x + v.y + v.z + v.w;
    float ss = v.x * v.x + v.y * v.y + v.z * v.z + v.w * v.w;
#pragma unroll
    for (int o = 32; o > 0; o >>= 1) { sm += __shfl_down(sm, o); ss += __shfl_down(ss, o); }
    __shared__ float red[8];
    int wid = t >> 6, lane = t & 63;
    if (lane == 0) { red[wid] = sm; red[4 + wid] = ss; }
    __syncthreads();
    if (t == 0) {
        float S = red[0] + red[1] + red[2];
        float SS = red[4] + red[5] + red[6];
        float mean = S * (1.f / 768.f);
        float var = SS * (1.f / 768.f) - mean * mean;
        red[0] = mean; red[1] = rsqrtf(var + 1e-5f);
    }
    __syncthreads();
    float mean = red[0], rst = red[1];
    *reinterpret_cast<float4*>(h + o0) = v;
    float4 wv = *reinterpret_cast<const float4*>(w + t * 4);
    float4 bv = *reinterpret_cast<const float4*>(b + t * 4);
    ushort4 o4;
    o4.x = f2bf((v.x - mean) * rst * wv.x + bv.x);
    o4.y = f2bf((v.y - mean) * rst * wv.y + bv.y);
    o4.z = f2bf((v.z - mean) * rst * wv.z + bv.z);
    o4.w = f2bf((v.w - mean) * rst * wv.w + bv.w);
    *reinterpret_cast<ushort4*>(x + (size_t)m * 768 + t * 4) = o4;
}

// ------------------------------------------------- transpose fp32[K][N] -> bf16[Npad][K]
__global__ void k_transpose(const float* __restrict__ W, unsigned short* __restrict__ Bt,
                            int K, int N, int Npad) {
    __shared__ float tile[64][65];
    int tx = threadIdx.x, ty = threadIdx.y;     // (16, 16)
    int n0 = blockIdx.x * 64, k0 = blockIdx.y * 64;
    size_t l = blockIdx.z;
    W += l * (size_t)K * N;
    Bt += l * (size_t)Npad * K;
    if (n0 + 64 <= N) {
#pragma unroll
        for (int i = 0; i < 4; i++) {
            int kr = ty * 4 + i;
            float4 v = *reinterpret_cast<const float4*>(W + (size_t)(k0 + kr) * N + n0 + tx * 4);
            tile[kr][tx * 4 + 0] = v.x;
            tile[kr][tx * 4 + 1] = v.y;
            tile[kr][tx * 4 + 2] = v.z;
            tile[kr][tx * 4 + 3] = v.w;
        }
    } else {
#pragma unroll
        for (int i = 0; i < 4; i++) {
            int kr = ty * 4 + i;
#pragma unroll
            for (int j = 0; j < 4; j++) {
                int n = n0 + tx * 4 + j;
                tile[kr][tx * 4 + j] = (n < N) ? W[(size_t)(k0 + kr) * N + n] : 0.f;
            }
        }
    }
    __syncthreads();
#pragma unroll
    for (int i = 0; i < 4; i++) {
        int n = n0 + ty * 4 + i;
        ushort4 o;
        o.x = f2bf(tile[tx * 4 + 0][ty * 4 + i]);
        o.y = f2bf(tile[tx * 4 + 1][ty * 4 + i]);
        o.z = f2bf(tile[tx * 4 + 2][ty * 4 + i]);
        o.w = f2bf(tile[tx * 4 + 3][ty * 4 + i]);
        *reinterpret_cast<ushort4*>(Bt + (size_t)n * K + k0 + tx * 4) = o;
    }
}

// ---------------------------------------------------------------- GEMM (mid-size)
template <int BM, int BIAS, int GELU, int OUTBF16, int SPLITK>
__launch_bounds__(256, 2)
__global__ void k_gemm(const unsigned short* __restrict__ A,
                       const unsigned short* __restrict__ Bt,
                       const float* __restrict__ bias,
                       void* __restrict__ out,
                       int M, int N, int K) {
    constexpr int MF = BM / 32;
    constexpr int HALF = (BM + 128) * 64;
    __shared__ char smem_raw[2 * HALF];

    int t = threadIdx.x;
    int bm = blockIdx.x, bn = blockIdx.y;
    int kc = (SPLITK > 1) ? blockIdx.z : 0;
    int KC = K / SPLITK;

    int rowA0 = bm * BM, rowB0 = bn * 128;
    int lane = t & 63, w = t >> 6;
    int wr = w >> 1, wc = w & 1;

    const unsigned short* ga0 = A  + (size_t)(rowA0 + (t >> 2)) * K + kc * KC + (t & 3) * 8;
    const unsigned short* ga1 = ga0 + (size_t)64 * K;
    const unsigned short* gb0 = Bt + (size_t)(rowB0 + (t >> 2)) * K + kc * KC + (t & 3) * 8;
    const unsigned short* gb1 = gb0 + (size_t)64 * K;

    auto stage = [&](int buf, int ktile) {
        char* dst = smem_raw + buf * HALF + t * 16;
        int kt = ktile * 32;
        GL2LDS(ga0 + kt, dst);
        if constexpr (BM == 128) GL2LDS(ga1 + kt, dst + 4096);
        char* dstB = dst + BM * 64;
        GL2LDS(gb0 + kt, dstB);
        GL2LDS(gb1 + kt, dstB + 4096);
    };

    f32x4_t acc[MF][4] = {};

    int rA = wr * (BM / 2) + (lane & 15);
    int rB = wc * 64 + (lane & 15);
    int kofs = (lane >> 4) * 8;

    const int NT = KC / 32;
    stage(0, 0);
    __syncthreads();
    int cur = 0;
    for (int kt = 0; kt < NT; kt++) {
        if (kt + 1 < NT) stage(cur ^ 1, kt + 1);
        const unsigned short* As = (const unsigned short*)(smem_raw + cur * HALF);
        const unsigned short* Bs = As + BM * 32;
        bf16x8_t a[MF], b[4];
#pragma unroll
        for (int m = 0; m < MF; m++)
            a[m] = *reinterpret_cast<const bf16x8_t*>(As + (rA + m * 16) * 32 + kofs);
#pragma unroll
        for (int n = 0; n < 4; n++)
            b[n] = *reinterpret_cast<const bf16x8_t*>(Bs + (rB + n * 16) * 32 + kofs);
#pragma unroll
        for (int m = 0; m < MF; m++)
#pragma unroll
            for (int n = 0; n < 4; n++)
                acc[m][n] = mfma16(a[m], b[n], acc[m][n]);
        __syncthreads();
        cur ^= 1;
    }

    if constexpr (OUTBF16) {
        int colBase = bn * 128 + wc * 64 + (lane & 15);
        int rowBase = bm * BM + wr * (BM / 2) + ((lane >> 4) << 2);
#pragma unroll
        for (int n = 0; n < 4; n++) {
            int col = colBase + n * 16;
            float bv = 0.f;
            if (BIAS) bv = bias[col];
#pragma unroll
            for (int m = 0; m < MF; m++) {
                int row0 = rowBase + m * 16;
#pragma unroll
                for (int r = 0; r < 4; r++) {
                    int row = row0 + r;
                    float v = acc[m][n][r] + bv;
                    if (GELU) v = 0.5f * v * (1.f + erff(v * 0.70710678118f));
                    ((unsigned short*)out)[(size_t)row * N + col] = f2bf(v);
                }
            }
        }
    } else {
        auto epi = (unsigned short (*)[16][72])smem_raw;
        unsigned short* op_base = (unsigned short*)out + (size_t)kc * M * N;
        int rowBase0 = bm * BM + wr * (BM / 2);
        int colBase0 = bn * 128 + wc * 64;
#pragma unroll
        for (int m = 0; m < MF; m++) {
#pragma unroll
            for (int n = 0; n < 4; n++)
#pragma unroll
                for (int r = 0; r < 4; r++)
                    epi[w][(lane >> 4) * 4 + r][n * 16 + (lane & 15)] = f2bf(acc[m][n][r]);
            __syncthreads();
#pragma unroll
            for (int rr = 0; rr < 4; rr++) {
                int lr = (lane >> 4) * 4 + rr;
                int grow = rowBase0 + m * 16 + lr;
                int gcol = colBase0 + (lane & 15) * 4;
                ushort4 v4 = *reinterpret_cast<ushort4*>(&epi[w][lr][(lane & 15) * 4]);
                *reinterpret_cast<ushort4*>(op_base + (size_t)grow * N + gcol) = v4;
            }
            __syncthreads();
        }
    }
}

// ---------------------------------------------------------------- lm-head GEMM (256^2 deep pipeline)
__launch_bounds__(512, 1)
__global__ void k_lm(const unsigned short* __restrict__ A,
                     const unsigned short* __restrict__ Bt,
                     float* __restrict__ out) {
    constexpr int K = 768;
    constexpr int NT = K / 64;                 // 12 K-tiles
    __shared__ char smem[131072];              // 2 x (A 32KB | B 32KB)

    int t = threadIdx.x;
    int bm = blockIdx.x, bn = blockIdx.y;      // natural order, bm fastest
    int lane = t & 63, w = t >> 6;
    int wm = w >> 2, wn = w & 3;               // 2 x 4 waves
    int q = lane >> 4, l15 = lane & 15, l7 = lane & 7;

    int srow = t >> 3;                         // 0..63 per issue
    int sslot = (t & 7) ^ (srow & 7);
    const unsigned short* gA = A  + (size_t)(bm * 256 + srow) * K + sslot * 8;
    const unsigned short* gB = Bt + (size_t)(bn * 256 + srow) * K + sslot * 8;

    auto stage = [&](int buf, int ktile) {
        char* dst = smem + buf * 65536 + t * 16;
        int ko = ktile * 64;
#pragma unroll
        for (int i = 0; i < 4; i++)
            GL2LDS(gA + (size_t)(i * 64) * K + ko, dst + i * 8192);
#pragma unroll
        for (int i = 0; i < 4; i++)
            GL2LDS(gB + (size_t)(i * 64) * K + ko, dst + 32768 + i * 8192);
    };

    f32x4_t acc[8][4] = {};

    stage(0, 0);
    int cur = 0;
    for (int kt = 0; kt < NT; kt++) {
        if (kt + 1 < NT) {
            stage(cur ^ 1, kt + 1);
            asm volatile("s_waitcnt vmcnt(8)" ::: "memory");
        } else {
            asm volatile("s_waitcnt vmcnt(0)" ::: "memory");
        }
        __builtin_amdgcn_s_barrier();
        asm volatile("" ::: "memory");
        const char* Ab = smem + cur * 65536;
        const char* Bb = Ab + 32768;

        bf16x8_t bfr[4][2];
#pragma unroll
        for (int nf = 0; nf < 4; nf++)
#pragma unroll
            for (int ks = 0; ks < 2; ks++) {
                int row = wn * 64 + nf * 16 + l15;
                int slot = (ks * 4 + q) ^ l7;
                bfr[nf][ks] = *reinterpret_cast<const bf16x8_t*>(Bb + row * 128 + slot * 16);
            }
#pragma unroll
        for (int p = 0; p < 4; p++) {
            bf16x8_t afr[2][2];
#pragma unroll
            for (int mi = 0; mi < 2; mi++)
#pragma unroll
                for (int ks = 0; ks < 2; ks++) {
                    int row = wm * 128 + (p * 2 + mi) * 16 + l15;
                    int slot = (ks * 4 + q) ^ l7;
                    afr[mi][ks] = *reinterpret_cast<const bf16x8_t*>(Ab + row * 128 + slot * 16);
                }
            asm volatile("s_waitcnt lgkmcnt(0)" ::: "memory");
            __builtin_amdgcn_sched_barrier(0);
            __builtin_amdgcn_s_setprio(1);
#pragma unroll
            for (int mi = 0; mi < 2; mi++)
#pragma unroll
                for (int nf = 0; nf < 4; nf++)
#pragma unroll
                    for (int ks = 0; ks < 2; ks++)
                        acc[p * 2 + mi][nf] = mfma16(afr[mi][ks], bfr[nf][ks], acc[p * 2 + mi][nf]);
            __builtin_amdgcn_s_setprio(0);
        }
        asm volatile("" ::: "memory");
        __builtin_amdgcn_s_barrier();
        cur ^= 1;
    }

    float* epi = (float*)smem + w * (16 * 68);
#pragma unroll
    for (int mf = 0; mf < 8; mf++) {
#pragma unroll
        for (int nf = 0; nf < 4; nf++)
#pragma unroll
            for (int r = 0; r < 4; r++)
                epi[(q * 4 + r) * 68 + nf * 16 + l15] = acc[mf][nf][r];
        asm volatile("s_waitcnt lgkmcnt(0)" ::: "memory");
#pragma unroll
        for (int rr = 0; rr < 4; rr++) {
            int lr = q * 4 + rr;
            int grow = bm * 256 + wm * 128 + mf * 16 + lr;
            int col0 = bn * 256 + wn * 64 + l15;
            float* op = out + (size_t)grow * 50257 + col0;
#pragma unroll
            for (int e = 0; e < 4; e++) {
                if (col0 + e * 16 < 50257) op[e * 16] = epi[lr * 68 + l15 + e * 16];
            }
        }
        asm volatile("s_waitcnt lgkmcnt(0)" ::: "memory");
    }
}

// ---------------------------------------------------------------- flash attention
// grid (16 q-tiles, 48 bh) = 768 blocks = exactly 3/CU. KV tile = 64.
// K staged in LDS (rule #21), swapped QK^T, defer-max THR=8, packed LDS writes.
__launch_bounds__(256, 3)
__global__ void k_attn(const unsigned short* __restrict__ qkv, unsigned short* __restrict__ y) {
    __shared__ unsigned short Kb[3][4096];       // [key=64][d=64], src-swizzled
    __shared__ unsigned short Vt[2][4096];       // [d=64][key=64], XOR-swizzled
    __shared__ unsigned short Ps[4][16 * 72];    // per-wave P rows [q][k], stride 72

    int bh = blockIdx.y;
    int b = bh / 12, h = bh % 12;
    int qt = blockIdx.x;
    int t = threadIdx.x, lane = t & 63, w = t >> 6;
    const size_t ldq = 2304;
    const unsigned short* base = qkv + (size_t)b * 1024 * ldq + h * 64;
    const unsigned short* Kg = base + 768;
    const unsigned short* Vg = base + 1536;

    int srow = t >> 3;
    int lslot = (t & 7) ^ (srow & 7);
    auto stageK = [&](int buf, int kt) {
#pragma unroll
        for (int i = 0; i < 2; i++) {
            const unsigned short* src = Kg + (size_t)(kt * 64 + i * 32 + srow) * ldq + lslot * 8;
            GL2LDS(src, (char*)&Kb[buf][0] + i * 4096 + t * 16);
        }
    };

    bf16x8_t qf[2];
    int qrow = qt * 64 + w * 16 + (lane & 15);
#pragma unroll
    for (int kb = 0; kb < 2; kb++)
        qf[kb] = *reinterpret_cast<const bf16x8_t*>(base + (size_t)qrow * ldq + kb * 32 + (lane >> 4) * 8);

    f32x4_t o[4] = {};
    float m = -1e30f, l = 0.f;      // running max / denom for q = lane&15
    const float scale = 0.125f;

    int g2 = lane & 31;
    int dbase = ((lane >> 5) + w * 2) * 8;
    union VU { uint4 v[2]; unsigned short e[16]; };   // e[i*8+j]: key 2*g2+i, d dbase+j
    VU vv, vvn;
    auto loadV = [&](VU& u, int kt) {
        const unsigned short* p0 = Vg + (size_t)(kt * 64 + 2 * g2) * ldq + dbase;
        u.v[0] = *reinterpret_cast<const uint4*>(p0);
        u.v[1] = *reinterpret_cast<const uint4*>(p0 + ldq);
    };
    loadV(vv, 0);
    stageK(0, 0);
    __syncthreads();

    int cur = 0;
    for (int kt = 0; kt < 16; kt++) {
        char* vbuf = (char*)&Vt[cur][0];
#pragma unroll
        for (int j = 0; j < 8; j++) {
            int d = dbase + j;
            uint32_t pk = (uint32_t)vv.e[j] | ((uint32_t)vv.e[8 + j] << 16);
            uint32_t byte = (uint32_t)(d * 128 + g2 * 4) ^ (uint32_t)((d & 7) << 4);
            *(uint32_t*)(vbuf + byte) = pk;
        }
        __syncthreads();
        if (kt < 15) {
            stageK((kt + 1) % 3, kt + 1);
            loadV(vvn, kt + 1);
        }
        const char* kbuf = (const char*)&Kb[kt % 3][0];
        f32x4_t s[4] = {};
#pragma unroll
        for (int kb = 0; kb < 2; kb++) {
#pragma unroll
            for (int n = 0; n < 4; n++) {
                int row = n * 16 + (lane & 15);
                int pslot = (kb * 4 + (lane >> 4)) ^ (lane & 7);
                bf16x8_t kf = *reinterpret_cast<const bf16x8_t*>(kbuf + row * 128 + pslot * 16);
                s[n] = mfma16(kf, qf[kb], s[n]);
            }
        }
        float tmax = s[0][0];
#pragma unroll
        for (int n = 0; n < 4; n++)
#pragma unroll
            for (int r = 0; r < 4; r++) tmax = fmaxf(tmax, s[n][r]);
        tmax = fmaxf(tmax, __shfl_xor(tmax, 16));
        tmax = fmaxf(tmax, __shfl_xor(tmax, 32));
        tmax *= scale;
        if (__any(tmax > m + 8.f)) {            // rescale path (runs ~once)
            float mnew = fmaxf(m, tmax);
            float corr = __expf(m - mnew);
            m = mnew;
            l *= corr;
#pragma unroll
            for (int r = 0; r < 4; r++) {
                float cr = __shfl(corr, (lane & 48) | ((lane >> 4) * 4 + r));
#pragma unroll
                for (int n = 0; n < 4; n++) o[n][r] *= cr;
            }
        }
        float psum = 0.f;
#pragma unroll
        for (int n = 0; n < 4; n++) {
            ushort4 pk;
            unsigned short* pp = (unsigned short*)&pk;
#pragma unroll
            for (int r = 0; r < 4; r++) {
                float p = __expf(s[n][r] * scale - m);
                psum += p;
                pp[r] = f2bf(p);
            }
            *reinterpret_cast<ushort4*>(&Ps[w][(lane & 15) * 72 + n * 16 + (lane >> 4) * 4]) = pk;
        }
        psum += __shfl_xor(psum, 16);
        psum += __shfl_xor(psum, 32);
        l += psum;
#pragma unroll
        for (int kb = 0; kb < 2; kb++) {
            bf16x8_t pf = *reinterpret_cast<const bf16x8_t*>(
                &Ps[w][(lane & 15) * 72 + kb * 32 + (lane >> 4) * 8]);
#pragma unroll
            for (int n = 0; n < 4; n++) {
                int d = n * 16 + (lane & 15);
                uint32_t byte = (uint32_t)(d * 128 + (kb * 32 + (lane >> 4) * 8) * 2)
                                ^ (uint32_t)((d & 7) << 4);
                bf16x8_t vf = *reinterpret_cast<const bf16x8_t*>(vbuf + byte);
                o[n] = mfma16(pf, vf, o[n]);
            }
        }
        vv = vvn;
        cur ^= 1;
    }
    float linv[4];
#pragma unroll
    for (int r = 0; r < 4; r++)
        linv[r] = 1.f / __shfl(l, (lane & 48) | ((lane >> 4) * 4 + r));
#pragma unroll
    for (int n = 0; n < 4; n++) {
#pragma unroll
        for (int r = 0; r < 4; r++) {
            float val = o[n][r] * linv[r];
            int row = qt * 64 + w * 16 + (lane >> 4) * 4 + r;
            y[((size_t)(b * 1024 + row)) * 768 + h * 64 + n * 16 + (lane & 15)] = f2bf(val);
        }
    }
}

// ---------------------------------------------------------------- host
extern "C" void kernel_launch(void* const* d_in, const int* in_sizes, int n_in,
                              void* d_out, int out_size, void* d_ws, size_t ws_size,
                              hipStream_t stream) {
    const int*   ids   = (const int*)d_in[0];
    const float* wte   = (const float*)d_in[1];
    const float* wpe   = (const float*)d_in[2];
    const float* ln1w  = (const float*)d_in[3];
    const float* ln1b  = (const float*)d_in[4];
    const float* attnw = (const float*)d_in[5];
    const float* attnb = (const float*)d_in[6];
    const float* atpw  = (const float*)d_in[7];
    const float* atpb  = (const float*)d_in[8];
    const float* ln2w  = (const float*)d_in[9];
    const float* ln2b  = (const float*)d_in[10];
    const float* fcw   = (const float*)d_in[11];
    const float* fcb   = (const float*)d_in[12];
    const float* pjw   = (const float*)d_in[13];
    const float* pjb   = (const float*)d_in[14];
    const float* lnfw  = (const float*)d_in[15];
    const float* lnfb  = (const float*)d_in[16];
    const float* lmw   = (const float*)d_in[17];
    float* out = (float*)d_out;

    char* ws = (char*)d_ws;
    size_t off = 0;
    auto alloc = [&](size_t bytes) -> void* {
        void* p = ws + off;
        off += (bytes + 255) & ~(size_t)255;
        return p;
    };
    float*          h      = (float*)alloc(4096ull * 768 * 4);
    unsigned short* x      = (unsigned short*)alloc(4096ull * 768 * 2);
    unsigned short* qkvb   = (unsigned short*)alloc(4096ull * 2304 * 2);
    unsigned short* y      = (unsigned short*)alloc(4096ull * 768 * 2);
    unsigned short* u      = (unsigned short*)alloc(4096ull * 3072 * 2);
    unsigned short* part   = (unsigned short*)alloc(4ull * 4096 * 768 * 2);
    unsigned short* attnwT = (unsigned short*)alloc(12ull * 2304 * 768 * 2);
    unsigned short* atpwT  = (unsigned short*)alloc(12ull * 768 * 768 * 2);
    unsigned short* fcwT   = (unsigned short*)alloc(12ull * 3072 * 768 * 2);
    unsigned short* pjwT   = (unsigned short*)alloc(12ull * 768 * 3072 * 2);
    unsigned short* lmwT   = (unsigned short*)alloc(50432ull * 768 * 2);

    dim3 tb(16, 16);
    k_transpose<<<dim3(2304 / 64, 768 / 64, 12), tb, 0, stream>>>(attnw, attnwT, 768, 2304, 2304);
    k_transpose<<<dim3(768 / 64, 768 / 64, 12), tb, 0, stream>>>(atpw, atpwT, 768, 768, 768);
    k_transpose<<<dim3(3072 / 64, 768 / 64, 12), tb, 0, stream>>>(fcw, fcwT, 768, 3072, 3072);
    k_transpose<<<dim3(768 / 64, 3072 / 64, 12), tb, 0, stream>>>(pjw, pjwT, 3072, 768, 768);
    k_transpose<<<dim3(50432 / 64, 768 / 64, 1), tb, 0, stream>>>(lmw, lmwT, 768, 50257, 50432);

    k_embed_ln<<<4096, 192, 0, stream>>>(ids, wte, wpe, ln1w, ln1b, h, x);

    for (int l = 0; l < 12; l++) {
        // qkv: 128^2 2-phase, bias bf16 epilogue (full-chip grid)
        k_gemm<128, 1, 0, 1, 1><<<dim3(32, 18), 256, 0, stream>>>(
            x, attnwT + (size_t)l * 2304 * 768, attnb + l * 2304, qkvb,
            4096, 2304, 768);
        k_attn<<<dim3(16, 48), 256, 0, stream>>>(qkvb, y);
        // atp: BM=64 split-K=2 bf16 partials
        k_gemm<64, 0, 0, 0, 2><<<dim3(64, 6, 2), 256, 0, stream>>>(
            y, atpwT + (size_t)l * 768 * 768, nullptr, part,
            4096, 768, 768);
        k_ln_red<2><<<4096, 192, 0, stream>>>(part, atpb + l * 768,
            ln2w + l * 768, ln2b + l * 768, h, x);
        // fc: 128^2 2-phase, bias+gelu bf16 epilogue
        k_gemm<128, 1, 1, 1, 1><<<dim3(32, 24), 256, 0, stream>>>(
            x, fcwT + (size_t)l * 3072 * 768, fcb + l * 3072, u,
            4096, 3072, 768);
        // pj: BM=128 split-K=4 bf16 partials (16 MFMA/step, 768 blocks)
        k_gemm<128, 0, 0, 0, 4><<<dim3(32, 6, 4), 256, 0, stream>>>(
            u, pjwT + (size_t)l * 768 * 3072, nullptr, part,
            4096, 768, 3072);
        const float* nw = (l < 11) ? ln1w + (l + 1) * 768 : lnfw;
        const float* nb = (l < 11) ? ln1b + (l + 1) * 768 : lnfb;
        k_ln_red<4><<<4096, 192, 0, stream>>>(part, pjb + l * 768, nw, nb, h, x);
    }
    k_lm<<<dim3(16, 197), 512, 0, stream>>>(x, lmwT, out);
}